// Round 2
// baseline (1469.015 us; speedup 1.0000x reference)
//
#include <hip/hip_runtime.h>
#include <math.h>

#define BATCH 4
#define SEQ   4096
#define DIM   1024
#define VEC   4

// ---- fused decoupled-lookback scan parameters ----
#define DSPLIT 2                 // d-dimension split
#define CHAINS (BATCH * DSPLIT)  // 8 independent scan chains
#define NCF    256               // chunks per chain
#define SF     (SEQ / NCF)       // 16 rows per chunk
#define DPC    (DIM / DSPLIT)    // 512 d's per block
#define FUSED_GRID (CHAINS * NCF)

typedef float f32x4 __attribute__((ext_vector_type(4)));
typedef float f32x2 __attribute__((ext_vector_type(2)));

// ws layout for fused path:
// [0 .. 16384)                  : ticket counter (int at 0) + flags (CHAINS*NCF ints at byte 64)
// [16384 .. 16384+8MiB)         : agg  (CHAINS*NCF*DPC float2)
// [16384+8MiB .. 16384+16MiB)   : incl (CHAINS*NCF*DPC float2)
#define FUSED_CTRL_BYTES 16384
#define FUSED_PANEL ((size_t)CHAINS * NCF * DPC)   // float2 elements per panel

__global__ void k_zero(int* __restrict__ p) {
    int i = blockIdx.x * blockDim.x + threadIdx.x;
    if (i < FUSED_CTRL_BYTES / 4) p[i] = 0;
}

// One kernel: local scan (x held in registers) + decoupled lookback + output.
// Ticket-ordered chunk ids make the lookback deadlock-free regardless of HW
// dispatch order: aggregate publication is wait-free, and every block only
// waits on blocks that started earlier.
template <bool CPLX>
__global__ __launch_bounds__(256, 4) void k_fused(
    const float* __restrict__ x,
    const float* __restrict__ phr, const float* __restrict__ phi,
    const float* __restrict__ pir, const float* __restrict__ pii,
    const float* __restrict__ hr,  const float* __restrict__ hi_,
    int* __restrict__ ctrl, float2* __restrict__ agg, float2* __restrict__ incl,
    float* __restrict__ out)
{
    __shared__ int s_tick;
    if (threadIdx.x == 0) s_tick = atomicAdd(ctrl, 1);
    __syncthreads();
    const int vid   = s_tick;
    const int chain = vid & (CHAINS - 1);
    const int c     = vid / CHAINS;
    const int b  = chain >> 1;
    const int dh = chain & 1;
    const int dl = threadIdx.x * 2;        // local d in [0, DPC)
    const int d  = dh * DPC + dl;          // global d
    int* flags = ctrl + 16;                // flags at byte 64

    // per-d params: a = p/|p| * exp(-|p|), bq = phazor_init
    float ar[2], ai[2], bqr[2], bqi[2];
    {
        float2 p_r = *reinterpret_cast<const float2*>(phr + d);
        float2 p_i = *reinterpret_cast<const float2*>(phi + d);
        float2 q_r = *reinterpret_cast<const float2*>(pir + d);
        float2 q_i = *reinterpret_cast<const float2*>(pii + d);
        float prv[2] = {p_r.x, p_r.y}, piv[2] = {p_i.x, p_i.y};
        float qrv[2] = {q_r.x, q_r.y}, qiv[2] = {q_i.x, q_i.y};
#pragma unroll
        for (int j = 0; j < 2; ++j) {
            float mag = sqrtf(prv[j] * prv[j] + piv[j] * piv[j]);
            float s = expf(-mag) / mag;
            ar[j] = prv[j] * s; ai[j] = piv[j] * s;
            bqr[j] = qrv[j];    bqi[j] = qiv[j];
        }
    }
    // A_S = a^SF (SF=16 -> 4 squarings)
    float ASr[2], ASi[2];
#pragma unroll
    for (int j = 0; j < 2; ++j) {
        float sr = ar[j], si = ai[j];
#pragma unroll
        for (int k = 0; k < 4; ++k) {
            float nr = sr * sr - si * si;
            si = 2.f * sr * si;
            sr = nr;
        }
        ASr[j] = sr; ASi[j] = si;
    }

    // load x chunk into registers, local scan in place (zero initial state)
    const float* xp = x + ((size_t)b * SEQ + (size_t)c * SF) * DIM + d;
    float yr[SF][2], yi[SF][2];
#pragma unroll
    for (int t = 0; t < SF; ++t) {
        float2 xv = *reinterpret_cast<const float2*>(xp + (size_t)t * DIM);
        yr[t][0] = xv.x; yr[t][1] = xv.y;
    }
    float Cr[2] = {0.f, 0.f}, Ci[2] = {0.f, 0.f};
#pragma unroll
    for (int t = 0; t < SF; ++t) {
#pragma unroll
        for (int j = 0; j < 2; ++j) {
            float xv = yr[t][j];
            float nr = fmaf(ar[j], Cr[j], fmaf(-ai[j], Ci[j], bqr[j] * xv));
            float ni = fmaf(ar[j], Ci[j], fmaf( ai[j], Cr[j], bqi[j] * xv));
            yr[t][j] = nr; yi[t][j] = ni;
            Cr[j] = nr; Ci[j] = ni;
        }
    }

    const size_t slot = ((size_t)chain * NCF + c) * DPC + dl;
    const int fidx = chain * NCF + c;
    if (c != NCF - 1) {
        // publish aggregate (wait-free)
        *reinterpret_cast<f32x4*>(agg + slot) = f32x4{Cr[0], Ci[0], Cr[1], Ci[1]};
        __syncthreads();
        if (threadIdx.x == 0) {
            __threadfence();
            __hip_atomic_store(&flags[fidx], 1, __ATOMIC_RELEASE, __HIP_MEMORY_SCOPE_AGENT);
        }
    }

    // lookback: P = state before this chunk
    float Pr[2], Pi[2];
    if (c == 0) {
        float2 hv_r = *reinterpret_cast<const float2*>(hr  + (size_t)b * DIM + d);
        float2 hv_i = *reinterpret_cast<const float2*>(hi_ + (size_t)b * DIM + d);
        Pr[0] = hv_r.x; Pr[1] = hv_r.y; Pi[0] = hv_i.x; Pi[1] = hv_i.y;
    } else {
        float Mr[2] = {1.f, 1.f}, Mi[2] = {0.f, 0.f};
        Pr[0] = Pr[1] = Pi[0] = Pi[1] = 0.f;
        int p = c - 1;
        const int fbase = chain * NCF;
        while (true) {
            int f = __hip_atomic_load(&flags[fbase + p], __ATOMIC_ACQUIRE,
                                      __HIP_MEMORY_SCOPE_AGENT);
            f = __builtin_amdgcn_readfirstlane(f);
            if (f == 0) { __builtin_amdgcn_s_sleep(8); continue; }
            const float2* src = (f == 2 ? incl : agg) + ((size_t)fbase + p) * DPC + dl;
            f32x4 g = *reinterpret_cast<const f32x4*>(src);
            float gr[2] = {g.x, g.z}, gi[2] = {g.y, g.w};
#pragma unroll
            for (int j = 0; j < 2; ++j) {
                Pr[j] = fmaf(Mr[j], gr[j], fmaf(-Mi[j], gi[j], Pr[j]));
                Pi[j] = fmaf(Mr[j], gi[j], fmaf( Mi[j], gr[j], Pi[j]));
            }
            if (f == 2) break;
#pragma unroll
            for (int j = 0; j < 2; ++j) {
                float nr = Mr[j] * ASr[j] - Mi[j] * ASi[j];
                Mi[j] = Mr[j] * ASi[j] + Mi[j] * ASr[j];
                Mr[j] = nr;
            }
            if (--p < 0) {
                float2 hv_r = *reinterpret_cast<const float2*>(hr  + (size_t)b * DIM + d);
                float2 hv_i = *reinterpret_cast<const float2*>(hi_ + (size_t)b * DIM + d);
                float hrv[2] = {hv_r.x, hv_r.y}, hiv[2] = {hv_i.x, hv_i.y};
#pragma unroll
                for (int j = 0; j < 2; ++j) {
                    Pr[j] = fmaf(Mr[j], hrv[j], fmaf(-Mi[j], hiv[j], Pr[j]));
                    Pi[j] = fmaf(Mr[j], hiv[j], fmaf( Mi[j], hrv[j], Pi[j]));
                }
                break;
            }
        }
    }

    // publish inclusive = y_last + A_S * P (before writing outputs!)
    if (c != NCF - 1) {
        float Ir[2], Ii[2];
#pragma unroll
        for (int j = 0; j < 2; ++j) {
            Ir[j] = fmaf(ASr[j], Pr[j], fmaf(-ASi[j], Pi[j], Cr[j]));
            Ii[j] = fmaf(ASr[j], Pi[j], fmaf( ASi[j], Pr[j], Ci[j]));
        }
        *reinterpret_cast<f32x4*>(incl + slot) = f32x4{Ir[0], Ii[0], Ir[1], Ii[1]};
        __syncthreads();
        if (threadIdx.x == 0) {
            __threadfence();
            __hip_atomic_store(&flags[fidx], 2, __ATOMIC_RELEASE, __HIP_MEMORY_SCOPE_AGENT);
        }
    }

    // outputs: out_t = y_t + a^(t+1) * P  (NT stores; out never re-read)
    float apr[2], api[2];
#pragma unroll
    for (int j = 0; j < 2; ++j) {
        apr[j] = ar[j] * Pr[j] - ai[j] * Pi[j];
        api[j] = ar[j] * Pi[j] + ai[j] * Pr[j];
    }
    const size_t obase = ((size_t)b * SEQ + (size_t)c * SF) * DIM + d;
#pragma unroll
    for (int t = 0; t < SF; ++t) {
        float orv[2], oiv[2];
#pragma unroll
        for (int j = 0; j < 2; ++j) {
            orv[j] = yr[t][j] + apr[j];
            oiv[j] = yi[t][j] + api[j];
            float nr = apr[j] * ar[j] - api[j] * ai[j];
            api[j] = apr[j] * ai[j] + api[j] * ar[j];
            apr[j] = nr;
        }
        if (CPLX) {
            f32x4 v = {orv[0], oiv[0], orv[1], oiv[1]};
            __builtin_nontemporal_store(
                v, reinterpret_cast<f32x4*>(out + 2 * (obase + (size_t)t * DIM)));
        } else {
            f32x2 v = {orv[0], orv[1]};
            __builtin_nontemporal_store(
                v, reinterpret_cast<f32x2*>(out + obase + (size_t)t * DIM));
        }
    }
}

// ------------------- fallback path (3-kernel chunked scan) -------------------

__device__ __forceinline__ void load_params4(
    const float* __restrict__ phr, const float* __restrict__ phi,
    const float* __restrict__ pir, const float* __restrict__ pii,
    int d0, float* ar, float* ai, float* br, float* bi)
{
    float4 p_r = *reinterpret_cast<const float4*>(phr + d0);
    float4 p_i = *reinterpret_cast<const float4*>(phi + d0);
    float4 q_r = *reinterpret_cast<const float4*>(pir + d0);
    float4 q_i = *reinterpret_cast<const float4*>(pii + d0);
    float prv[VEC] = {p_r.x, p_r.y, p_r.z, p_r.w};
    float piv[VEC] = {p_i.x, p_i.y, p_i.z, p_i.w};
    float qrv[VEC] = {q_r.x, q_r.y, q_r.z, q_r.w};
    float qiv[VEC] = {q_i.x, q_i.y, q_i.z, q_i.w};
#pragma unroll
    for (int j = 0; j < VEC; ++j) {
        float mag = sqrtf(prv[j] * prv[j] + piv[j] * piv[j]);
        float s = expf(-mag) / mag;
        ar[j] = prv[j] * s;
        ai[j] = piv[j] * s;
        br[j] = qrv[j];
        bi[j] = qiv[j];
    }
}

template <int NC>
__global__ __launch_bounds__(256, 4) void k_carry(
    const float* __restrict__ x,
    const float* __restrict__ phr, const float* __restrict__ phi,
    const float* __restrict__ pir, const float* __restrict__ pii,
    float2* __restrict__ carry)
{
    constexpr int S = SEQ / NC;
    const int d0 = (blockIdx.x * blockDim.x + threadIdx.x) * VEC;
    const int c = blockIdx.y, b = blockIdx.z;

    float ar[VEC], ai[VEC], br[VEC], bi[VEC];
    load_params4(phr, phi, pir, pii, d0, ar, ai, br, bi);

    const float* xp = x + ((size_t)b * SEQ + (size_t)c * S) * DIM + d0;
    float Cr[VEC] = {0.f, 0.f, 0.f, 0.f};
    float Ci[VEC] = {0.f, 0.f, 0.f, 0.f};
#pragma unroll 4
    for (int t = 0; t < S; ++t) {
        float4 xv = *reinterpret_cast<const float4*>(xp + (size_t)t * DIM);
        float xa[VEC] = {xv.x, xv.y, xv.z, xv.w};
#pragma unroll
        for (int j = 0; j < VEC; ++j) {
            float nr = fmaf(ar[j], Cr[j], fmaf(-ai[j], Ci[j], br[j] * xa[j]));
            float ni = fmaf(ar[j], Ci[j], fmaf( ai[j], Cr[j], bi[j] * xa[j]));
            Cr[j] = nr; Ci[j] = ni;
        }
    }
    float2* cp = carry + ((size_t)b * NC + c) * DIM + d0;
#pragma unroll
    for (int j = 0; j < VEC; ++j) cp[j] = make_float2(Cr[j], Ci[j]);
}

template <int NC>
__global__ __launch_bounds__(64) void k_prefix(
    const float* __restrict__ phr, const float* __restrict__ phi,
    const float* __restrict__ hr,  const float* __restrict__ hi_,
    const float2* __restrict__ carry,
    float2* __restrict__ prefix)
{
    constexpr int S = SEQ / NC;
    const int idx = blockIdx.x * blockDim.x + threadIdx.x;
    const int b = idx / DIM, d = idx % DIM;

    float pr = phr[d], pi = phi[d];
    float mag = sqrtf(pr * pr + pi * pi);
    float sc = expf(-mag) / mag;
    float ar = pr * sc, ai = pi * sc;

    float Ar = 1.f, Ai = 0.f, sr = ar, si = ai;
    int e = S;
    while (e) {
        if (e & 1) {
            float nr = Ar * sr - Ai * si;
            Ai = Ar * si + Ai * sr;
            Ar = nr;
        }
        float nr = sr * sr - si * si;
        si = 2.f * sr * si;
        sr = nr;
        e >>= 1;
    }

    float Pr = hr[idx], Pi = hi_[idx];
    constexpr int TILE = 8;
    static_assert(NC % TILE == 0, "NC must be a multiple of TILE");
    for (int base = 0; base < NC; base += TILE) {
        float2 cv[TILE];
#pragma unroll
        for (int k = 0; k < TILE; ++k)
            cv[k] = carry[((size_t)b * NC + base + k) * DIM + d];
#pragma unroll
        for (int k = 0; k < TILE; ++k) {
            prefix[((size_t)b * NC + base + k) * DIM + d] = make_float2(Pr, Pi);
            float nr = fmaf(Ar, Pr, fmaf(-Ai, Pi, cv[k].x));
            float ni = fmaf(Ar, Pi, fmaf( Ai, Pr, cv[k].y));
            Pr = nr; Pi = ni;
        }
    }
}

template <int NC, bool CPLX>
__global__ __launch_bounds__(256, 4) void k_out(
    const float* __restrict__ x,
    const float* __restrict__ phr, const float* __restrict__ phi,
    const float* __restrict__ pir, const float* __restrict__ pii,
    const float2* __restrict__ prefix,
    float* __restrict__ out)
{
    constexpr int S = SEQ / NC;
    const int d0 = (blockIdx.x * blockDim.x + threadIdx.x) * VEC;
    const int c = blockIdx.y, b = blockIdx.z;

    float ar[VEC], ai[VEC], br[VEC], bi[VEC];
    load_params4(phr, phi, pir, pii, d0, ar, ai, br, bi);

    float Cr[VEC], Ci[VEC];
    const float2* pp = prefix + ((size_t)b * NC + c) * DIM + d0;
#pragma unroll
    for (int j = 0; j < VEC; ++j) {
        float2 v = pp[j];
        Cr[j] = v.x; Ci[j] = v.y;
    }

    const float* xp = x + ((size_t)b * SEQ + (size_t)c * S) * DIM + d0;
    const size_t obase = ((size_t)b * SEQ + (size_t)c * S) * DIM + d0;
#pragma unroll 4
    for (int t = 0; t < S; ++t) {
        float4 xv = *reinterpret_cast<const float4*>(xp + (size_t)t * DIM);
        float xa[VEC] = {xv.x, xv.y, xv.z, xv.w};
#pragma unroll
        for (int j = 0; j < VEC; ++j) {
            float nr = fmaf(ar[j], Cr[j], fmaf(-ai[j], Ci[j], br[j] * xa[j]));
            float ni = fmaf(ar[j], Ci[j], fmaf( ai[j], Cr[j], bi[j] * xa[j]));
            Cr[j] = nr; Ci[j] = ni;
        }
        if (CPLX) {
            f32x4* dst = reinterpret_cast<f32x4*>(out + 2 * (obase + (size_t)t * DIM));
            f32x4 v0 = {Cr[0], Ci[0], Cr[1], Ci[1]};
            f32x4 v1 = {Cr[2], Ci[2], Cr[3], Ci[3]};
            __builtin_nontemporal_store(v0, dst);
            __builtin_nontemporal_store(v1, dst + 1);
        } else {
            f32x4* dst = reinterpret_cast<f32x4*>(out + obase + (size_t)t * DIM);
            f32x4 v0 = {Cr[0], Cr[1], Cr[2], Cr[3]};
            __builtin_nontemporal_store(v0, dst);
        }
    }
}

template <bool CPLX>
__global__ void k_serial(
    const float* __restrict__ x,
    const float* __restrict__ phr, const float* __restrict__ phi,
    const float* __restrict__ pir, const float* __restrict__ pii,
    const float* __restrict__ hr,  const float* __restrict__ hi_,
    float* __restrict__ out)
{
    const int idx = blockIdx.x * blockDim.x + threadIdx.x;
    if (idx >= BATCH * DIM) return;
    const int b = idx / DIM, d = idx % DIM;

    float pr = phr[d], pi = phi[d];
    float mag = sqrtf(pr * pr + pi * pi);
    float sc = expf(-mag) / mag;
    float ar = pr * sc, ai = pi * sc;
    float br = pir[d], bi = pii[d];

    float Cr = hr[idx], Ci = hi_[idx];
    const float* xp = x + (size_t)b * SEQ * DIM + d;
    for (int t = 0; t < SEQ; ++t) {
        float xv = xp[(size_t)t * DIM];
        float nr = fmaf(ar, Cr, fmaf(-ai, Ci, br * xv));
        float ni = fmaf(ar, Ci, fmaf( ai, Cr, bi * xv));
        Cr = nr; Ci = ni;
        size_t o = ((size_t)b * SEQ + t) * DIM + d;
        if (CPLX) {
            reinterpret_cast<float2*>(out)[o] = make_float2(Cr, Ci);
        } else {
            out[o] = Cr;
        }
    }
}

template <int NC, bool CPLX>
static void run_all(const float* x, const float* hr, const float* hi_,
                    const float* phr, const float* phi,
                    const float* pir, const float* pii,
                    float* out, void* d_ws, hipStream_t stream)
{
    float2* carry = (float2*)d_ws;
    float2* prefix = carry + (size_t)BATCH * NC * DIM;

    dim3 blk(256);
    dim3 g1(DIM / (256 * VEC), NC, BATCH);
    k_carry<NC><<<g1, blk, 0, stream>>>(x, phr, phi, pir, pii, carry);
    k_prefix<NC><<<dim3(BATCH * DIM / 64), dim3(64), 0, stream>>>(
        phr, phi, hr, hi_, carry, prefix);
    k_out<NC, CPLX><<<g1, blk, 0, stream>>>(x, phr, phi, pir, pii, prefix, out);
}

template <bool CPLX>
static void dispatch(const float* x, const float* hr, const float* hi_,
                     const float* phr, const float* phi,
                     const float* pir, const float* pii,
                     float* out, void* d_ws, size_t ws_size, hipStream_t stream)
{
    const size_t need_fused = FUSED_CTRL_BYTES + 2 * FUSED_PANEL * sizeof(float2);
    if (ws_size >= need_fused) {
        int* ctrl = (int*)d_ws;
        float2* agg  = (float2*)((char*)d_ws + FUSED_CTRL_BYTES);
        float2* incl = agg + FUSED_PANEL;
        k_zero<<<dim3(FUSED_CTRL_BYTES / 4 / 256), dim3(256), 0, stream>>>(ctrl);
        k_fused<CPLX><<<dim3(FUSED_GRID), dim3(256), 0, stream>>>(
            x, phr, phi, pir, pii, hr, hi_, ctrl, agg, incl, out);
        return;
    }

    auto need = [](int nc) { return (size_t)2 * BATCH * nc * DIM * sizeof(float2); };
    if (ws_size >= need(64))
        run_all<64, CPLX>(x, hr, hi_, phr, phi, pir, pii, out, d_ws, stream);
    else if (ws_size >= need(32))
        run_all<32, CPLX>(x, hr, hi_, phr, phi, pir, pii, out, d_ws, stream);
    else if (ws_size >= need(16))
        run_all<16, CPLX>(x, hr, hi_, phr, phi, pir, pii, out, d_ws, stream);
    else
        k_serial<CPLX><<<dim3((BATCH * DIM + 255) / 256), dim3(256), 0, stream>>>(
            x, phr, phi, pir, pii, hr, hi_, out);
}

extern "C" void kernel_launch(void* const* d_in, const int* in_sizes, int n_in,
                              void* d_out, int out_size, void* d_ws, size_t ws_size,
                              hipStream_t stream) {
    const float* x   = (const float*)d_in[0];
    const float* hr  = (const float*)d_in[1];
    const float* hi_ = (const float*)d_in[2];
    const float* phr = (const float*)d_in[3];
    const float* phi = (const float*)d_in[4];
    const float* pir = (const float*)d_in[5];
    const float* pii = (const float*)d_in[6];
    float* out = (float*)d_out;

    const size_t total = (size_t)BATCH * SEQ * DIM;
    if ((size_t)out_size >= 2 * total)
        dispatch<true >(x, hr, hi_, phr, phi, pir, pii, out, d_ws, ws_size, stream);
    else
        dispatch<false>(x, hr, hi_, phr, phi, pir, pii, out, d_ws, ws_size, stream);
}

// Round 3
// 160.042 us; speedup vs baseline: 9.1789x; 9.1789x over previous
//
#include <hip/hip_runtime.h>
#include <math.h>

#define BATCH 4
#define SEQ   4096
#define DIM   1024
#define VEC   4

// 2-kernel chunked scan: NC2 chunks of S2 rows.
#define NC2 128
#define S2  (SEQ / NC2)   // 32

typedef float f32x4 __attribute__((ext_vector_type(4)));
typedef float f32x2 __attribute__((ext_vector_type(2)));

// Per-d parameters: a = phazor = p/|p| * exp(-|p|), b = phazor_init.
__device__ __forceinline__ void load_params4(
    const float* __restrict__ phr, const float* __restrict__ phi,
    const float* __restrict__ pir, const float* __restrict__ pii,
    int d0, float* ar, float* ai, float* br, float* bi)
{
    float4 p_r = *reinterpret_cast<const float4*>(phr + d0);
    float4 p_i = *reinterpret_cast<const float4*>(phi + d0);
    float4 q_r = *reinterpret_cast<const float4*>(pir + d0);
    float4 q_i = *reinterpret_cast<const float4*>(pii + d0);
    float prv[VEC] = {p_r.x, p_r.y, p_r.z, p_r.w};
    float piv[VEC] = {p_i.x, p_i.y, p_i.z, p_i.w};
    float qrv[VEC] = {q_r.x, q_r.y, q_r.z, q_r.w};
    float qiv[VEC] = {q_i.x, q_i.y, q_i.z, q_i.w};
#pragma unroll
    for (int j = 0; j < VEC; ++j) {
        float mag = sqrtf(prv[j] * prv[j] + piv[j] * piv[j]);
        float s = expf(-mag) / mag;
        ar[j] = prv[j] * s;
        ai[j] = piv[j] * s;
        br[j] = qrv[j];
        bi[j] = qiv[j];
    }
}

// K1: per-chunk local scan with zero initial state -> chunk carries.
// Block (c, b): 256 threads x VEC=4 d's = full DIM. Carries stay cacheable
// (re-read by K2 from L2/L3).
__global__ __launch_bounds__(256, 2) void k1_carry(
    const float* __restrict__ x,
    const float* __restrict__ phr, const float* __restrict__ phi,
    const float* __restrict__ pir, const float* __restrict__ pii,
    float2* __restrict__ carry)
{
    const int d0 = threadIdx.x * VEC;
    const int c = blockIdx.x, b = blockIdx.y;

    float ar[VEC], ai[VEC], br[VEC], bi[VEC];
    load_params4(phr, phi, pir, pii, d0, ar, ai, br, bi);

    const float* xp = x + ((size_t)b * SEQ + (size_t)c * S2) * DIM + d0;
    float Cr[VEC] = {0.f, 0.f, 0.f, 0.f};
    float Ci[VEC] = {0.f, 0.f, 0.f, 0.f};
#pragma unroll 4
    for (int t = 0; t < S2; ++t) {
        float4 xv = *reinterpret_cast<const float4*>(xp + (size_t)t * DIM);
        float xa[VEC] = {xv.x, xv.y, xv.z, xv.w};
#pragma unroll
        for (int j = 0; j < VEC; ++j) {
            float nr = fmaf(ar[j], Cr[j], fmaf(-ai[j], Ci[j], br[j] * xa[j]));
            float ni = fmaf(ar[j], Ci[j], fmaf( ai[j], Cr[j], bi[j] * xa[j]));
            Cr[j] = nr; Ci[j] = ni;
        }
    }
    f32x4* cp = reinterpret_cast<f32x4*>(carry + ((size_t)b * NC2 + c) * DIM + d0);
    cp[0] = f32x4{Cr[0], Ci[0], Cr[1], Ci[1]};
    cp[1] = f32x4{Cr[2], Ci[2], Cr[3], Ci[3]};
}

// K2: block (c, b) computes its own seed P redundantly (stream carries k<c
// with a register power chain M *= A^S2 -- loads are independent, no
// memory-latency-serial chain), then runs the seeded output scan over its
// x chunk (L3-hot after K1). NT stores for out (never re-read; protects
// x + carries in L2/L3).
template <bool CPLX>
__global__ __launch_bounds__(256, 2) void k2_out(
    const float* __restrict__ x,
    const float* __restrict__ phr, const float* __restrict__ phi,
    const float* __restrict__ pir, const float* __restrict__ pii,
    const float* __restrict__ hr,  const float* __restrict__ hi_,
    const float2* __restrict__ carry,
    float* __restrict__ out)
{
    const int d0 = threadIdx.x * VEC;
    const int c = blockIdx.x, b = blockIdx.y;

    float ar[VEC], ai[VEC], bqr[VEC], bqi[VEC];
    load_params4(phr, phi, pir, pii, d0, ar, ai, bqr, bqi);

    // A_S = a^S2 (S2=32 -> 5 squarings)
    float ASr[VEC], ASi[VEC];
#pragma unroll
    for (int j = 0; j < VEC; ++j) {
        float sr = ar[j], si = ai[j];
#pragma unroll
        for (int k = 0; k < 5; ++k) {
            float nr = sr * sr - si * si;
            si = 2.f * sr * si;
            sr = nr;
        }
        ASr[j] = sr; ASi[j] = si;
    }

    // Seed: P = sum_{k<c} A_S^{c-1-k} * carry_k + A_S^c * h
    float Pr[VEC] = {0.f, 0.f, 0.f, 0.f}, Pi[VEC] = {0.f, 0.f, 0.f, 0.f};
    float Mr[VEC] = {1.f, 1.f, 1.f, 1.f}, Mi[VEC] = {0.f, 0.f, 0.f, 0.f};
    const float2* cb = carry + (size_t)b * NC2 * DIM + d0;
#pragma unroll 4
    for (int k = c - 1; k >= 0; --k) {
        const f32x4* src = reinterpret_cast<const f32x4*>(cb + (size_t)k * DIM);
        f32x4 g0 = src[0], g1 = src[1];
        float gr[VEC] = {g0.x, g0.z, g1.x, g1.z};
        float gi[VEC] = {g0.y, g0.w, g1.y, g1.w};
#pragma unroll
        for (int j = 0; j < VEC; ++j) {
            Pr[j] = fmaf(Mr[j], gr[j], fmaf(-Mi[j], gi[j], Pr[j]));
            Pi[j] = fmaf(Mr[j], gi[j], fmaf( Mi[j], gr[j], Pi[j]));
            float nr = Mr[j] * ASr[j] - Mi[j] * ASi[j];
            Mi[j] = Mr[j] * ASi[j] + Mi[j] * ASr[j];
            Mr[j] = nr;
        }
    }
    {
        float4 hv_r = *reinterpret_cast<const float4*>(hr  + (size_t)b * DIM + d0);
        float4 hv_i = *reinterpret_cast<const float4*>(hi_ + (size_t)b * DIM + d0);
        float hrv[VEC] = {hv_r.x, hv_r.y, hv_r.z, hv_r.w};
        float hiv[VEC] = {hv_i.x, hv_i.y, hv_i.z, hv_i.w};
#pragma unroll
        for (int j = 0; j < VEC; ++j) {
            Pr[j] = fmaf(Mr[j], hrv[j], fmaf(-Mi[j], hiv[j], Pr[j]));
            Pi[j] = fmaf(Mr[j], hiv[j], fmaf( Mi[j], hrv[j], Pi[j]));
        }
    }

    // Seeded output scan over this chunk.
    float Cr[VEC], Ci[VEC];
#pragma unroll
    for (int j = 0; j < VEC; ++j) { Cr[j] = Pr[j]; Ci[j] = Pi[j]; }

    const float* xp = x + ((size_t)b * SEQ + (size_t)c * S2) * DIM + d0;
    const size_t obase = ((size_t)b * SEQ + (size_t)c * S2) * DIM + d0;
#pragma unroll 4
    for (int t = 0; t < S2; ++t) {
        float4 xv = *reinterpret_cast<const float4*>(xp + (size_t)t * DIM);
        float xa[VEC] = {xv.x, xv.y, xv.z, xv.w};
#pragma unroll
        for (int j = 0; j < VEC; ++j) {
            float nr = fmaf(ar[j], Cr[j], fmaf(-ai[j], Ci[j], bqr[j] * xa[j]));
            float ni = fmaf(ar[j], Ci[j], fmaf( ai[j], Cr[j], bqi[j] * xa[j]));
            Cr[j] = nr; Ci[j] = ni;
        }
        if (CPLX) {
            f32x4* dst = reinterpret_cast<f32x4*>(out + 2 * (obase + (size_t)t * DIM));
            f32x4 v0 = {Cr[0], Ci[0], Cr[1], Ci[1]};
            f32x4 v1 = {Cr[2], Ci[2], Cr[3], Ci[3]};
            __builtin_nontemporal_store(v0, dst);
            __builtin_nontemporal_store(v1, dst + 1);
        } else {
            f32x4 v0 = {Cr[0], Cr[1], Cr[2], Cr[3]};
            __builtin_nontemporal_store(
                v0, reinterpret_cast<f32x4*>(out + obase + (size_t)t * DIM));
        }
    }
}

// Scratch-free fallback: one thread per (b,d), serial scan over all of SEQ.
template <bool CPLX>
__global__ void k_serial(
    const float* __restrict__ x,
    const float* __restrict__ phr, const float* __restrict__ phi,
    const float* __restrict__ pir, const float* __restrict__ pii,
    const float* __restrict__ hr,  const float* __restrict__ hi_,
    float* __restrict__ out)
{
    const int idx = blockIdx.x * blockDim.x + threadIdx.x;  // b*DIM + d
    if (idx >= BATCH * DIM) return;
    const int b = idx / DIM, d = idx % DIM;

    float pr = phr[d], pi = phi[d];
    float mag = sqrtf(pr * pr + pi * pi);
    float sc = expf(-mag) / mag;
    float ar = pr * sc, ai = pi * sc;
    float br = pir[d], bi = pii[d];

    float Cr = hr[idx], Ci = hi_[idx];
    const float* xp = x + (size_t)b * SEQ * DIM + d;
    for (int t = 0; t < SEQ; ++t) {
        float xv = xp[(size_t)t * DIM];
        float nr = fmaf(ar, Cr, fmaf(-ai, Ci, br * xv));
        float ni = fmaf(ar, Ci, fmaf( ai, Cr, bi * xv));
        Cr = nr; Ci = ni;
        size_t o = ((size_t)b * SEQ + t) * DIM + d;
        if (CPLX) {
            reinterpret_cast<float2*>(out)[o] = make_float2(Cr, Ci);
        } else {
            out[o] = Cr;
        }
    }
}

template <bool CPLX>
static void dispatch(const float* x, const float* hr, const float* hi_,
                     const float* phr, const float* phi,
                     const float* pir, const float* pii,
                     float* out, void* d_ws, size_t ws_size, hipStream_t stream)
{
    const size_t need = (size_t)BATCH * NC2 * DIM * sizeof(float2);  // 4 MiB
    if (ws_size >= need) {
        float2* carry = (float2*)d_ws;
        dim3 blk(256);
        dim3 g(NC2, BATCH);
        k1_carry<<<g, blk, 0, stream>>>(x, phr, phi, pir, pii, carry);
        k2_out<CPLX><<<g, blk, 0, stream>>>(
            x, phr, phi, pir, pii, hr, hi_, carry, out);
    } else {
        k_serial<CPLX><<<dim3((BATCH * DIM + 255) / 256), dim3(256), 0, stream>>>(
            x, phr, phi, pir, pii, hr, hi_, out);
    }
}

extern "C" void kernel_launch(void* const* d_in, const int* in_sizes, int n_in,
                              void* d_out, int out_size, void* d_ws, size_t ws_size,
                              hipStream_t stream) {
    const float* x   = (const float*)d_in[0];
    const float* hr  = (const float*)d_in[1];
    const float* hi_ = (const float*)d_in[2];
    const float* phr = (const float*)d_in[3];
    const float* phi = (const float*)d_in[4];
    const float* pir = (const float*)d_in[5];
    const float* pii = (const float*)d_in[6];
    float* out = (float*)d_out;

    const size_t total = (size_t)BATCH * SEQ * DIM;
    // out_size >= 2*total  -> buffer holds interleaved complex64 (re,im pairs)
    // otherwise            -> buffer holds exactly total floats: write real part
    if ((size_t)out_size >= 2 * total)
        dispatch<true >(x, hr, hi_, phr, phi, pir, pii, out, d_ws, ws_size, stream);
    else
        dispatch<false>(x, hr, hi_, phr, phi, pir, pii, out, d_ws, ws_size, stream);
}